// Round 8
// baseline (290.604 us; speedup 1.0000x reference)
//
#include <hip/hip_runtime.h>

// ---------------------------------------------------------------------------
// QueryGNN: 2-layer GCN on MI355X (gfx950), bf16-MFMA, async-LDS GEMM.
//   h1   = bf16(x) @ W1 + b1         (MFMA, f32 A staged+converted, out bf16)
//   h1ln = relu(LN(agg(h1)))         (multi-edge gather + LN + ReLU, bf16)
//   h2   = h1ln @ W2 + b2            (MFMA, out bf16)
//   out  = LN(agg(h2))               (fused, f32)
// GEMM geometry: BM=64, BN=N (grid=ceil(M/64), gy=1) -> ~3 blocks/CU,
// A read exactly once; double-buffered global_load_lds staging.
// ---------------------------------------------------------------------------

constexpr float LN_EPS = 1e-5f;

typedef __attribute__((ext_vector_type(8))) short short8;
typedef __attribute__((ext_vector_type(4))) float f32x4;

static __device__ __forceinline__ unsigned short f2bf(float f) {
    unsigned u = __float_as_uint(f);
    u += 0x7FFFu + ((u >> 16) & 1u);          // RNE
    return (unsigned short)(u >> 16);
}
static __device__ __forceinline__ float bf2f(unsigned short h) {
    return __uint_as_float(((unsigned)h) << 16);
}
static __device__ __forceinline__ short8 f2bf8(float4 a, float4 b) {
    short8 r;
    r[0] = (short)f2bf(a.x); r[1] = (short)f2bf(a.y);
    r[2] = (short)f2bf(a.z); r[3] = (short)f2bf(a.w);
    r[4] = (short)f2bf(b.x); r[5] = (short)f2bf(b.y);
    r[6] = (short)f2bf(b.z); r[7] = (short)f2bf(b.w);
    return r;
}

#if defined(__has_builtin)
#if __has_builtin(__builtin_amdgcn_global_load_lds)
#define HAS_GLL 1
#endif
#endif

#ifdef HAS_GLL
static __device__ __forceinline__ void gll16(const void* g, void* l) {
    __builtin_amdgcn_global_load_lds(
        (__attribute__((address_space(1))) void*)g,
        (__attribute__((address_space(3))) void*)l, 16, 0, 0);
}
#endif

// ---------------- degree histogram (weighted deg + edge count) --------------
__global__ __launch_bounds__(256) void k_deg_hist(
    const int* __restrict__ row, const float* __restrict__ ew,
    float* __restrict__ deg, int* __restrict__ cnt, int E)
{
    int e = blockIdx.x * 256 + threadIdx.x;
    if (e >= E) return;
    int r = row[e];
    atomicAdd(deg + r, ew[e]);
    atomicAdd(cnt + r, 1);
}

// ---------------- dis = rsqrt(deg) AND per-block sum of cnt -----------------
__global__ __launch_bounds__(256) void k_dis_part(
    const float* __restrict__ deg, float* __restrict__ dis,
    const int* __restrict__ cnt, int* __restrict__ part, int n)
{
    int i = blockIdx.x * 256 + threadIdx.x;
    if (i < n) {
        float d = deg[i];
        dis[i] = d > 0.0f ? rsqrtf(d) : 0.0f;
    }
    int v = (i < n) ? cnt[i] : 0;
    #pragma unroll
    for (int off = 32; off; off >>= 1) v += __shfl_xor(v, off);
    __shared__ int ws[4];
    if ((threadIdx.x & 63) == 0) ws[threadIdx.x >> 6] = v;
    __syncthreads();
    if (threadIdx.x == 0) part[blockIdx.x] = ws[0] + ws[1] + ws[2] + ws[3];
}

__global__ __launch_bounds__(256) void k_scanpart(int* part, int nparts)
{
    int t = threadIdx.x;
    int v = (t < nparts) ? part[t] : 0;
    __shared__ int s[256];
    s[t] = v; __syncthreads();
    for (int off = 1; off < 256; off <<= 1) {
        int u = (t >= off) ? s[t - off] : 0;
        __syncthreads();
        s[t] += u;
        __syncthreads();
    }
    if (t < nparts) part[t] = s[t] - v;   // exclusive
}

__global__ __launch_bounds__(256) void k_rowptr(
    int* __restrict__ cnt, const int* __restrict__ part,
    int* __restrict__ rowptr, int n)
{
    int t = threadIdx.x;
    int i = blockIdx.x * 256 + t;
    int v = (i < n) ? cnt[i] : 0;
    __shared__ int s[256];
    s[t] = v; __syncthreads();
    for (int off = 1; off < 256; off <<= 1) {
        int u = (t >= off) ? s[t - off] : 0;
        __syncthreads();
        s[t] += u;
        __syncthreads();
    }
    if (i < n) {
        int base = part[blockIdx.x];
        int ex = base + s[t] - v;
        rowptr[i] = ex;
        cnt[i] = ex;                      // re-init as fill cursor
        if (i == n - 1) rowptr[n] = base + s[t];
    }
}

// ---------------- CSR fill: packed (col, norm) per destination row ----------
__global__ __launch_bounds__(256) void k_scatter(
    const int* __restrict__ row, const int* __restrict__ col,
    const float* __restrict__ ew, const float* __restrict__ dis,
    int* __restrict__ cursor, int2* __restrict__ edges, int E)
{
    int e = blockIdx.x * 256 + threadIdx.x;
    if (e >= E) return;
    int r = row[e], c = col[e];
    int p = atomicAdd(cursor + r, 1);
    edges[p] = make_int2(c, __float_as_int(dis[r] * ew[e] * dis[c]));
}

// ---------------- both weight transposes, f32 -> bf16, one launch -----------
__global__ __launch_bounds__(256) void k_wt(
    const float* __restrict__ W1, const float* __restrict__ W2,
    unsigned short* __restrict__ W1T, unsigned short* __restrict__ W2T)
{
    constexpr int K1 = 384, N1 = 256, K2 = 256, N2 = 128;
    int o = blockIdx.x * 256 + threadIdx.x;
    if (o < K1 * N1) {
        int n = o / K1, k = o - n * K1;
        W1T[o] = f2bf(W1[(size_t)k * N1 + n]);
    } else {
        int o2 = o - K1 * N1;
        if (o2 < K2 * N2) {
            int n = o2 / K2, k = o2 - n * K2;
            W2T[o2] = f2bf(W2[(size_t)k * N2 + n]);
        }
    }
}

// ---------------- bf16 MFMA GEMM: C[M,BN] = A[M,K] @ BT^T + bias ------------
// A [M,K] row-major (f32 if AF32, else bf16); BT [BN,K] bf16 row-major.
// BM=64, gy=1 (BN = full N). 256 threads = 4 waves, wave w covers cols
// [w*BN/4, (w+1)*BN/4): 4 M-frags x NF N-frags of v_mfma_f32_16x16x32_bf16.
// Double-buffered LDS, async global_load_lds, one barrier per K-step.
template<bool AF32, int BN>
__global__ __launch_bounds__(256) void k_gemm_mfma(
    const void* __restrict__ Av, const unsigned short* __restrict__ BT,
    const float* __restrict__ bias, unsigned short* __restrict__ C,
    int M, int K)
{
    constexpr int BM = 64, BK = 32;
    constexpr int NF = BN / 64;                    // N-frags per wave
    constexpr int AB = (AF32 ? 4 : 2) * BM * BK;   // A tile bytes (8K/4K)
    constexpr int BB = 2 * BN * BK;                // B tile bytes (16K/8K)
    constexpr int ASL = AB / 16;                   // 16B slots
    constexpr int BSL = BB / 16;
    constexpr int ACH = AF32 ? 8 : 4;              // 16B chunks per A row

    __shared__ char smem[2 * (AB + BB)];

    const int t    = threadIdx.x;
    const int lane = t & 63;
    const int wid  = t >> 6;
    const int row0 = blockIdx.x * BM;
    const int fr   = lane & 15;
    const int fq   = lane >> 4;
    const int nb   = wid * (BN / 4);

    const float*          Af = (const float*)Av;
    const unsigned short* Ab = (const unsigned short*)Av;

    const int nt = K / BK;
    f32x4 acc[4][NF] = {};

    // ---- staging: per-thread global sources, linear LDS destinations ----
    // A slot s: row = s/ACH, chunk = s%ACH (16B). B slot s: row = s/4, chunk = s%4.
    auto srcA = [&](int s, int k0) -> const void* {
        int r = s / ACH, ch = s - r * ACH;
        int gr = row0 + r; if (gr >= M) gr = M - 1;
        if constexpr (AF32) return (const void*)(Af + (size_t)gr * K + k0 + ch * 4);
        else                return (const void*)(Ab + (size_t)gr * K + k0 + ch * 8);
    };
    auto srcB = [&](int s, int k0) -> const void* {
        int r = s >> 2, ch = s & 3;
        return (const void*)(BT + (size_t)r * K + k0 + ch * 8);
    };

    auto compute = [&](char* As, char* Bs) {
        short8 af[4], bfr[NF];
        #pragma unroll
        for (int i = 0; i < 4; ++i) {
            const int r = i * 16 + fr;
            if constexpr (AF32) {
                const float* p = (const float*)As + r * BK + fq * 8;
                float4 u0 = *(const float4*)p;
                float4 u1 = *(const float4*)(p + 4);
                af[i] = f2bf8(u0, u1);
            } else {
                af[i] = *(const short8*)((const unsigned short*)As + r * BK + fq * 8);
            }
        }
        #pragma unroll
        for (int j = 0; j < NF; ++j)
            bfr[j] = *(const short8*)((const unsigned short*)Bs
                                      + (nb + j * 16 + fr) * BK + fq * 8);
        #pragma unroll
        for (int i = 0; i < 4; ++i)
            #pragma unroll
            for (int j = 0; j < NF; ++j)
                acc[i][j] = __builtin_amdgcn_mfma_f32_16x16x32_bf16(
                    af[i], bfr[j], acc[i][j], 0, 0, 0);
    };

#ifdef HAS_GLL
    auto stage = [&](int buf, int k0) {
        char* As = smem + buf * (AB + BB);
        char* Bs = As + AB;
        #pragma unroll
        for (int c = 0; c < ASL / 256; ++c) {
            const int s = c * 256 + t;
            gll16(srcA(s, k0), As + s * 16);
        }
        #pragma unroll
        for (int c = 0; c < BSL / 256; ++c) {
            const int s = c * 256 + t;
            gll16(srcB(s, k0), Bs + s * 16);
        }
    };

    stage(0, 0);
    __syncthreads();                       // buf0 staged (vmcnt drained)
    int cur = 0;
    for (int st = 0; st < nt; ++st) {
        if (st + 1 < nt) stage(cur ^ 1, (st + 1) * BK);   // async next tile
        char* As = smem + cur * (AB + BB);
        compute(As, As + AB);
        __syncthreads();                   // drains vmcnt -> next buf ready
        cur ^= 1;
    }
#else
    // fallback: reg-staged single buffer, classic 2-barrier loop
    char* As = smem;
    char* Bs = smem + AB;
    for (int st = 0; st < nt; ++st) {
        const int k0 = st * BK;
        int4 ar[ASL / 256], br[BSL / 256];
        #pragma unroll
        for (int c = 0; c < ASL / 256; ++c)
            ar[c] = *(const int4*)srcA(c * 256 + t, k0);
        #pragma unroll
        for (int c = 0; c < BSL / 256; ++c)
            br[c] = *(const int4*)srcB(c * 256 + t, k0);
        __syncthreads();
        #pragma unroll
        for (int c = 0; c < ASL / 256; ++c)
            *(int4*)(As + (c * 256 + t) * 16) = ar[c];
        #pragma unroll
        for (int c = 0; c < BSL / 256; ++c)
            *(int4*)(Bs + (c * 256 + t) * 16) = br[c];
        __syncthreads();
        compute(As, Bs);
    }
#endif

    // ---- epilogue: C/D mapping col = lane&15, row = (lane>>4)*4 + reg ----
    #pragma unroll
    for (int i = 0; i < 4; ++i) {
        #pragma unroll
        for (int j = 0; j < NF; ++j) {
            const int c = nb + j * 16 + fr;
            const float bvv = bias[c];
            #pragma unroll
            for (int r = 0; r < 4; ++r) {
                const int rr = row0 + i * 16 + fq * 4 + r;
                if (rr < M)
                    C[(size_t)rr * BN + c] = f2bf(acc[i][j][r] + bvv);
            }
        }
    }
}

// ---------------- fused pull-aggregation + layernorm (+relu) ----------------
// one wave per destination node; EPI edges per iteration, 16B/lane gathers.
template<int D, bool RELU, bool OUTBF>
__global__ __launch_bounds__(256) void k_agg_ln(
    const unsigned short* __restrict__ feat, const int* __restrict__ rowptr,
    const int2* __restrict__ edges,
    const float* __restrict__ g, const float* __restrict__ b,
    void* __restrict__ outv, int n)
{
    constexpr int LPR = D / 8;        // lanes per feature row (32 or 16)
    constexpr int EPI = 64 / LPR;     // edges per iteration (2 or 4)
    const int gw   = (blockIdx.x * 256 + threadIdx.x) >> 6;
    const int lane = threadIdx.x & 63;
    if (gw >= n) return;

    const int sub = lane / LPR;       // edge slot within group
    const int el  = (lane % LPR) * 8; // element offset within row

    float acc[8] = {};
    const int j0 = rowptr[gw], j1 = rowptr[gw + 1];
    #pragma unroll 2
    for (int j = j0; j < j1; j += EPI) {
        const int jj = j + sub;
        float wv = 0.0f;
        int   c  = 0;
        if (jj < j1) {
            int2 e = edges[jj];
            c  = e.x;
            wv = __int_as_float(e.y);
        }
        const short8 u = *(const short8*)(feat + (size_t)c * D + el);
        #pragma unroll
        for (int i = 0; i < 8; ++i)
            acc[i] += wv * bf2f((unsigned short)u[i]);
    }

    // merge edge-slot partials
    #pragma unroll
    for (int off = LPR; off < 64; off <<= 1)
        #pragma unroll
        for (int i = 0; i < 8; ++i)
            acc[i] += __shfl_xor(acc[i], off);

    // stats (each element replicated EPI times across the wave)
    float s = 0.0f;
    #pragma unroll
    for (int i = 0; i < 8; ++i) s += acc[i];
    #pragma unroll
    for (int off = 32; off; off >>= 1) s += __shfl_xor(s, off);
    const float m = s * (1.0f / (EPI * D));

    float q = 0.0f;
    #pragma unroll
    for (int i = 0; i < 8; ++i) { float d = acc[i] - m; q += d * d; }
    #pragma unroll
    for (int off = 32; off; off >>= 1) q += __shfl_xor(q, off);
    const float r = rsqrtf(q * (1.0f / (EPI * D)) + LN_EPS);

    if (lane < LPR) {
        float4 g0 = *(const float4*)(g + el);
        float4 g1 = *(const float4*)(g + el + 4);
        float4 b0 = *(const float4*)(b + el);
        float4 b1 = *(const float4*)(b + el + 4);
        float gg[8] = {g0.x, g0.y, g0.z, g0.w, g1.x, g1.y, g1.z, g1.w};
        float bb[8] = {b0.x, b0.y, b0.z, b0.w, b1.x, b1.y, b1.z, b1.w};
        float o[8];
        #pragma unroll
        for (int i = 0; i < 8; ++i) {
            float tv = (acc[i] - m) * r * gg[i] + bb[i];
            if constexpr (RELU) tv = fmaxf(tv, 0.0f);
            o[i] = tv;
        }
        if constexpr (OUTBF) {
            short8 u;
            #pragma unroll
            for (int i = 0; i < 8; ++i) u[i] = (short)f2bf(o[i]);
            *(short8*)((unsigned short*)outv + (size_t)gw * D + el) = u;
        } else {
            float* op = (float*)outv + (size_t)gw * D + el;
            *(float4*)(op)     = make_float4(o[0], o[1], o[2], o[3]);
            *(float4*)(op + 4) = make_float4(o[4], o[5], o[6], o[7]);
        }
    }
}

// ---------------------------------------------------------------------------
extern "C" void kernel_launch(void* const* d_in, const int* in_sizes, int n_in,
                              void* d_out, int out_size, void* d_ws, size_t ws_size,
                              hipStream_t stream)
{
    (void)n_in; (void)out_size; (void)ws_size;

    constexpr int DIN = 384, DH = 256, DOUT = 128;

    const float* x   = (const float*)d_in[0];
    const int*   ei  = (const int*)  d_in[1];
    const float* ew  = (const float*)d_in[2];
    const float* W1  = (const float*)d_in[3];
    const float* b1  = (const float*)d_in[4];
    const float* W2  = (const float*)d_in[5];
    const float* b2  = (const float*)d_in[6];
    const float* g1  = (const float*)d_in[7];
    const float* be1 = (const float*)d_in[8];
    const float* g2  = (const float*)d_in[9];
    const float* be2 = (const float*)d_in[10];
    float* out = (float*)d_out;

    const int N = in_sizes[0] / DIN;
    const int E = in_sizes[2];
    const int* row = ei;
    const int* col = ei + E;

    // ---- workspace carve (256B aligned) ----
    char* w = (char*)d_ws;
    auto carve = [&](size_t bytes) {
        char* p = w;
        w += (bytes + 255) & ~(size_t)255;
        return p;
    };
    float*          deg    = (float*)carve((size_t)N * 4);
    float*          dis    = (float*)carve((size_t)N * 4);
    int*            cnt    = (int*)  carve((size_t)N * 4);
    int*            rowptr = (int*)  carve((size_t)(N + 1) * 4);
    int*            part   = (int*)  carve(256 * 4);
    int2*           edges  = (int2*) carve((size_t)E * 8);
    unsigned short* W1T    = (unsigned short*)carve((size_t)DIN * DH * 2);
    unsigned short* W2T    = (unsigned short*)carve((size_t)DH * DOUT * 2);
    unsigned short* h1     = (unsigned short*)carve((size_t)N * DH * 2);
    unsigned short* h1ln   = (unsigned short*)carve((size_t)N * DH * 2);
    unsigned short* h2     = (unsigned short*)carve((size_t)N * DOUT * 2);

    const int gE = (E + 255) / 256;
    const int gN = (N + 255) / 256;     // nparts for scan (N<=65536)
    const int gW = (N + 3) / 4;         // one wave per node, 4 waves/block
    const int gG = (N + 63) / 64;       // GEMM blocks (BM=64)

    // ---- graph preprocessing: deg, dis, CSR ----
    hipMemsetAsync(deg, 0, (size_t)N * 4, stream);
    hipMemsetAsync(cnt, 0, (size_t)N * 4, stream);
    k_deg_hist<<<gE, 256, 0, stream>>>(row, ew, deg, cnt, E);
    k_dis_part<<<gN, 256, 0, stream>>>(deg, dis, cnt, part, N);
    k_scanpart<<<1, 256, 0, stream>>>(part, gN);
    k_rowptr  <<<gN, 256, 0, stream>>>(cnt, part, rowptr, N);
    k_scatter <<<gE, 256, 0, stream>>>(row, col, ew, dis, cnt, edges, E);

    // ---- weights -> bf16 transposed (one launch) ----
    k_wt<<<(DIN * DH + DH * DOUT + 255) / 256, 256, 0, stream>>>(W1, W2, W1T, W2T);

    // ---- layer 1: h1 = bf16(x) @ W1 + b1 ----
    k_gemm_mfma<true, DH><<<gG, 256, 0, stream>>>(x, W1T, b1, h1, N, DIN);
    k_agg_ln<DH, true, true><<<gW, 256, 0, stream>>>(h1, rowptr, edges,
                                                     g1, be1, h1ln, N);

    // ---- layer 2: h2 = h1ln @ W2 + b2 ----
    k_gemm_mfma<false, DOUT><<<gG, 256, 0, stream>>>(h1ln, W2T, b2, h2, N, DH);
    k_agg_ln<DOUT, false, false><<<gW, 256, 0, stream>>>(h2, rowptr, edges,
                                                         g2, be2, out, N);
}

// Round 9
// 225.872 us; speedup vs baseline: 1.2866x; 1.2866x over previous
//
#include <hip/hip_runtime.h>

// ---------------------------------------------------------------------------
// QueryGNN: 2-layer GCN on MI355X (gfx950), bf16-MFMA, async-LDS GEMM.
//   preprocessing: ONE packed 64-bit atomic per edge (cnt<<32 | Q8.24 deg),
//   returned old value's hi32 = per-row ordinal -> atomic-free CSR fill.
//   h1   = bf16(x) @ W1 + b1         (MFMA, f32 A staged+converted, out bf16)
//   h1ln = relu(LN(agg(h1)))         (multi-edge gather + LN + ReLU, bf16)
//   h2   = h1ln @ W2 + b2            (MFMA, out bf16)
//   out  = LN(agg(h2))               (fused, f32)
// ---------------------------------------------------------------------------

constexpr float LN_EPS = 1e-5f;

typedef __attribute__((ext_vector_type(8))) short short8;
typedef __attribute__((ext_vector_type(4))) float f32x4;

static __device__ __forceinline__ unsigned short f2bf(float f) {
    unsigned u = __float_as_uint(f);
    u += 0x7FFFu + ((u >> 16) & 1u);          // RNE
    return (unsigned short)(u >> 16);
}
static __device__ __forceinline__ float bf2f(unsigned short h) {
    return __uint_as_float(((unsigned)h) << 16);
}
static __device__ __forceinline__ short8 f2bf8(float4 a, float4 b) {
    short8 r;
    r[0] = (short)f2bf(a.x); r[1] = (short)f2bf(a.y);
    r[2] = (short)f2bf(a.z); r[3] = (short)f2bf(a.w);
    r[4] = (short)f2bf(b.x); r[5] = (short)f2bf(b.y);
    r[6] = (short)f2bf(b.z); r[7] = (short)f2bf(b.w);
    return r;
}

#if defined(__has_builtin)
#if __has_builtin(__builtin_amdgcn_global_load_lds)
#define HAS_GLL 1
#endif
#endif

#ifdef HAS_GLL
static __device__ __forceinline__ void gll16(const void* g, void* l) {
    __builtin_amdgcn_global_load_lds(
        (__attribute__((address_space(1))) void*)g,
        (__attribute__((address_space(3))) void*)l, 16, 0, 0);
}
#endif

// ---------------- packed histogram: ONE atomic per edge ---------------------
// packed[r] hi32 = edge count, lo32 = Q8.24 fixed-point weighted degree.
// Returned old hi32 = this edge's ordinal within row r (CSR slot offset).
__global__ __launch_bounds__(256) void k_hist(
    const int* __restrict__ row, const float* __restrict__ ew,
    unsigned long long* __restrict__ packed, int* __restrict__ ord, int E)
{
    int e = blockIdx.x * 256 + threadIdx.x;
    if (e >= E) return;
    int r = row[e];
    unsigned fx = __float2uint_rn(ew[e] * 16777216.0f);   // Q8.24
    unsigned long long old =
        atomicAdd(packed + r, (1ULL << 32) | (unsigned long long)fx);
    ord[e] = (int)(old >> 32);
}

// ---------------- dis = rsqrt(deg) AND per-block sum of cnt -----------------
__global__ __launch_bounds__(256) void k_dis_part(
    const unsigned long long* __restrict__ packed, float* __restrict__ dis,
    int* __restrict__ part, int n)
{
    int i = blockIdx.x * 256 + threadIdx.x;
    int v = 0;
    if (i < n) {
        unsigned long long p = packed[i];
        float d = (float)(unsigned)(p & 0xFFFFFFFFu) * (1.0f / 16777216.0f);
        dis[i] = d > 0.0f ? rsqrtf(d) : 0.0f;
        v = (int)(p >> 32);
    }
    #pragma unroll
    for (int off = 32; off; off >>= 1) v += __shfl_xor(v, off);
    __shared__ int ws[4];
    if ((threadIdx.x & 63) == 0) ws[threadIdx.x >> 6] = v;
    __syncthreads();
    if (threadIdx.x == 0) part[blockIdx.x] = ws[0] + ws[1] + ws[2] + ws[3];
}

__global__ __launch_bounds__(256) void k_scanpart(int* part, int nparts)
{
    int t = threadIdx.x;
    int v = (t < nparts) ? part[t] : 0;
    __shared__ int s[256];
    s[t] = v; __syncthreads();
    for (int off = 1; off < 256; off <<= 1) {
        int u = (t >= off) ? s[t - off] : 0;
        __syncthreads();
        s[t] += u;
        __syncthreads();
    }
    if (t < nparts) part[t] = s[t] - v;   // exclusive
}

__global__ __launch_bounds__(256) void k_rowptr(
    const unsigned long long* __restrict__ packed, const int* __restrict__ part,
    int* __restrict__ rowptr, int n)
{
    int t = threadIdx.x;
    int i = blockIdx.x * 256 + t;
    int v = (i < n) ? (int)(packed[i] >> 32) : 0;
    __shared__ int s[256];
    s[t] = v; __syncthreads();
    for (int off = 1; off < 256; off <<= 1) {
        int u = (t >= off) ? s[t - off] : 0;
        __syncthreads();
        s[t] += u;
        __syncthreads();
    }
    if (i < n) {
        int base = part[blockIdx.x];
        rowptr[i] = base + s[t] - v;
        if (i == n - 1) rowptr[n] = base + s[t];
    }
}

// ---------------- CSR fill, atomic-free: slot = rowptr[r] + ord[e] ----------
__global__ __launch_bounds__(256) void k_scatter(
    const int* __restrict__ row, const int* __restrict__ col,
    const float* __restrict__ ew, const float* __restrict__ dis,
    const int* __restrict__ rowptr, const int* __restrict__ ord,
    int2* __restrict__ edges, int E)
{
    int e = blockIdx.x * 256 + threadIdx.x;
    if (e >= E) return;
    int r = row[e], c = col[e];
    int p = rowptr[r] + ord[e];
    edges[p] = make_int2(c, __float_as_int(dis[r] * ew[e] * dis[c]));
}

// ---------------- both weight transposes, f32 -> bf16, one launch -----------
__global__ __launch_bounds__(256) void k_wt(
    const float* __restrict__ W1, const float* __restrict__ W2,
    unsigned short* __restrict__ W1T, unsigned short* __restrict__ W2T)
{
    constexpr int K1 = 384, N1 = 256, K2 = 256, N2 = 128;
    int o = blockIdx.x * 256 + threadIdx.x;
    if (o < K1 * N1) {
        int n = o / K1, k = o - n * K1;
        W1T[o] = f2bf(W1[(size_t)k * N1 + n]);
    } else {
        int o2 = o - K1 * N1;
        if (o2 < K2 * N2) {
            int n = o2 / K2, k = o2 - n * K2;
            W2T[o2] = f2bf(W2[(size_t)k * N2 + n]);
        }
    }
}

// ---------------- bf16 MFMA GEMM: C[M,BN] = A[M,K] @ BT^T + bias ------------
// A [M,K] row-major (f32 if AF32, else bf16); BT [BN,K] bf16 row-major.
// BM=64, gy=1 (BN = full N). 256 threads = 4 waves, wave w covers cols
// [w*BN/4, (w+1)*BN/4): 4 M-frags x NF N-frags of v_mfma_f32_16x16x32_bf16.
// Double-buffered LDS, async global_load_lds, one barrier per K-step.
template<bool AF32, int BN>
__global__ __launch_bounds__(256) void k_gemm_mfma(
    const void* __restrict__ Av, const unsigned short* __restrict__ BT,
    const float* __restrict__ bias, unsigned short* __restrict__ C,
    int M, int K)
{
    constexpr int BM = 64, BK = 32;
    constexpr int NF = BN / 64;                    // N-frags per wave
    constexpr int AB = (AF32 ? 4 : 2) * BM * BK;   // A tile bytes (8K/4K)
    constexpr int BB = 2 * BN * BK;                // B tile bytes (16K/8K)
    constexpr int ASL = AB / 16;                   // 16B slots
    constexpr int BSL = BB / 16;
    constexpr int ACH = AF32 ? 8 : 4;              // 16B chunks per A row

    __shared__ char smem[2 * (AB + BB)];

    const int t    = threadIdx.x;
    const int lane = t & 63;
    const int wid  = t >> 6;
    const int row0 = blockIdx.x * BM;
    const int fr   = lane & 15;
    const int fq   = lane >> 4;
    const int nb   = wid * (BN / 4);

    const float*          Af = (const float*)Av;
    const unsigned short* Ab = (const unsigned short*)Av;

    const int nt = K / BK;
    f32x4 acc[4][NF] = {};

    auto srcA = [&](int s, int k0) -> const void* {
        int r = s / ACH, ch = s - r * ACH;
        int gr = row0 + r; if (gr >= M) gr = M - 1;
        if constexpr (AF32) return (const void*)(Af + (size_t)gr * K + k0 + ch * 4);
        else                return (const void*)(Ab + (size_t)gr * K + k0 + ch * 8);
    };
    auto srcB = [&](int s, int k0) -> const void* {
        int r = s >> 2, ch = s & 3;
        return (const void*)(BT + (size_t)r * K + k0 + ch * 8);
    };

    auto compute = [&](char* As, char* Bs) {
        short8 af[4], bfr[NF];
        #pragma unroll
        for (int i = 0; i < 4; ++i) {
            const int r = i * 16 + fr;
            if constexpr (AF32) {
                const float* p = (const float*)As + r * BK + fq * 8;
                float4 u0 = *(const float4*)p;
                float4 u1 = *(const float4*)(p + 4);
                af[i] = f2bf8(u0, u1);
            } else {
                af[i] = *(const short8*)((const unsigned short*)As + r * BK + fq * 8);
            }
        }
        #pragma unroll
        for (int j = 0; j < NF; ++j)
            bfr[j] = *(const short8*)((const unsigned short*)Bs
                                      + (nb + j * 16 + fr) * BK + fq * 8);
        #pragma unroll
        for (int i = 0; i < 4; ++i)
            #pragma unroll
            for (int j = 0; j < NF; ++j)
                acc[i][j] = __builtin_amdgcn_mfma_f32_16x16x32_bf16(
                    af[i], bfr[j], acc[i][j], 0, 0, 0);
    };

#ifdef HAS_GLL
    auto stage = [&](int buf, int k0) {
        char* As = smem + buf * (AB + BB);
        char* Bs = As + AB;
        #pragma unroll
        for (int c = 0; c < ASL / 256; ++c) {
            const int s = c * 256 + t;
            gll16(srcA(s, k0), As + s * 16);
        }
        #pragma unroll
        for (int c = 0; c < BSL / 256; ++c) {
            const int s = c * 256 + t;
            gll16(srcB(s, k0), Bs + s * 16);
        }
    };

    stage(0, 0);
    __syncthreads();                       // buf0 staged (vmcnt drained)
    int cur = 0;
    for (int st = 0; st < nt; ++st) {
        if (st + 1 < nt) stage(cur ^ 1, (st + 1) * BK);   // async next tile
        char* As = smem + cur * (AB + BB);
        compute(As, As + AB);
        __syncthreads();                   // drains vmcnt -> next buf ready
        cur ^= 1;
    }
#else
    // fallback: reg-staged single buffer, classic 2-barrier loop
    char* As = smem;
    char* Bs = smem + AB;
    for (int st = 0; st < nt; ++st) {
        const int k0 = st * BK;
        int4 ar[ASL / 256], br[BSL / 256];
        #pragma unroll
        for (int c = 0; c < ASL / 256; ++c)
            ar[c] = *(const int4*)srcA(c * 256 + t, k0);
        #pragma unroll
        for (int c = 0; c < BSL / 256; ++c)
            br[c] = *(const int4*)srcB(c * 256 + t, k0);
        __syncthreads();
        #pragma unroll
        for (int c = 0; c < ASL / 256; ++c)
            *(int4*)(As + (c * 256 + t) * 16) = ar[c];
        #pragma unroll
        for (int c = 0; c < BSL / 256; ++c)
            *(int4*)(Bs + (c * 256 + t) * 16) = br[c];
        __syncthreads();
        compute(As, Bs);
    }
#endif

    // ---- epilogue: C/D mapping col = lane&15, row = (lane>>4)*4 + reg ----
    #pragma unroll
    for (int i = 0; i < 4; ++i) {
        #pragma unroll
        for (int j = 0; j < NF; ++j) {
            const int c = nb + j * 16 + fr;
            const float bvv = bias[c];
            #pragma unroll
            for (int r = 0; r < 4; ++r) {
                const int rr = row0 + i * 16 + fq * 4 + r;
                if (rr < M)
                    C[(size_t)rr * BN + c] = f2bf(acc[i][j][r] + bvv);
            }
        }
    }
}

// ---------------- fused pull-aggregation + layernorm (+relu) ----------------
// one wave per destination node; EPI edges per iteration, 16B/lane gathers.
template<int D, bool RELU, bool OUTBF>
__global__ __launch_bounds__(256) void k_agg_ln(
    const unsigned short* __restrict__ feat, const int* __restrict__ rowptr,
    const int2* __restrict__ edges,
    const float* __restrict__ g, const float* __restrict__ b,
    void* __restrict__ outv, int n)
{
    constexpr int LPR = D / 8;        // lanes per feature row (32 or 16)
    constexpr int EPI = 64 / LPR;     // edges per iteration (2 or 4)
    const int gw   = (blockIdx.x * 256 + threadIdx.x) >> 6;
    const int lane = threadIdx.x & 63;
    if (gw >= n) return;

    const int sub = lane / LPR;       // edge slot within group
    const int el  = (lane % LPR) * 8; // element offset within row

    float acc[8] = {};
    const int j0 = rowptr[gw], j1 = rowptr[gw + 1];
    #pragma unroll 2
    for (int j = j0; j < j1; j += EPI) {
        const int jj = j + sub;
        float wv = 0.0f;
        int   c  = 0;
        if (jj < j1) {
            int2 e = edges[jj];
            c  = e.x;
            wv = __int_as_float(e.y);
        }
        const short8 u = *(const short8*)(feat + (size_t)c * D + el);
        #pragma unroll
        for (int i = 0; i < 8; ++i)
            acc[i] += wv * bf2f((unsigned short)u[i]);
    }

    // merge edge-slot partials
    #pragma unroll
    for (int off = LPR; off < 64; off <<= 1)
        #pragma unroll
        for (int i = 0; i < 8; ++i)
            acc[i] += __shfl_xor(acc[i], off);

    // stats (each element replicated EPI times across the wave)
    float s = 0.0f;
    #pragma unroll
    for (int i = 0; i < 8; ++i) s += acc[i];
    #pragma unroll
    for (int off = 32; off; off >>= 1) s += __shfl_xor(s, off);
    const float m = s * (1.0f / (EPI * D));

    float q = 0.0f;
    #pragma unroll
    for (int i = 0; i < 8; ++i) { float d = acc[i] - m; q += d * d; }
    #pragma unroll
    for (int off = 32; off; off >>= 1) q += __shfl_xor(q, off);
    const float r = rsqrtf(q * (1.0f / (EPI * D)) + LN_EPS);

    if (lane < LPR) {
        float4 g0 = *(const float4*)(g + el);
        float4 g1 = *(const float4*)(g + el + 4);
        float4 b0 = *(const float4*)(b + el);
        float4 b1 = *(const float4*)(b + el + 4);
        float gg[8] = {g0.x, g0.y, g0.z, g0.w, g1.x, g1.y, g1.z, g1.w};
        float bb[8] = {b0.x, b0.y, b0.z, b0.w, b1.x, b1.y, b1.z, b1.w};
        float o[8];
        #pragma unroll
        for (int i = 0; i < 8; ++i) {
            float tv = (acc[i] - m) * r * gg[i] + bb[i];
            if constexpr (RELU) tv = fmaxf(tv, 0.0f);
            o[i] = tv;
        }
        if constexpr (OUTBF) {
            short8 u;
            #pragma unroll
            for (int i = 0; i < 8; ++i) u[i] = (short)f2bf(o[i]);
            *(short8*)((unsigned short*)outv + (size_t)gw * D + el) = u;
        } else {
            float* op = (float*)outv + (size_t)gw * D + el;
            *(float4*)(op)     = make_float4(o[0], o[1], o[2], o[3]);
            *(float4*)(op + 4) = make_float4(o[4], o[5], o[6], o[7]);
        }
    }
}

// ---------------------------------------------------------------------------
extern "C" void kernel_launch(void* const* d_in, const int* in_sizes, int n_in,
                              void* d_out, int out_size, void* d_ws, size_t ws_size,
                              hipStream_t stream)
{
    (void)n_in; (void)out_size; (void)ws_size;

    constexpr int DIN = 384, DH = 256, DOUT = 128;

    const float* x   = (const float*)d_in[0];
    const int*   ei  = (const int*)  d_in[1];
    const float* ew  = (const float*)d_in[2];
    const float* W1  = (const float*)d_in[3];
    const float* b1  = (const float*)d_in[4];
    const float* W2  = (const float*)d_in[5];
    const float* b2  = (const float*)d_in[6];
    const float* g1  = (const float*)d_in[7];
    const float* be1 = (const float*)d_in[8];
    const float* g2  = (const float*)d_in[9];
    const float* be2 = (const float*)d_in[10];
    float* out = (float*)d_out;

    const int N = in_sizes[0] / DIN;
    const int E = in_sizes[2];
    const int* row = ei;
    const int* col = ei + E;

    // ---- workspace carve (256B aligned) ----
    char* w = (char*)d_ws;
    auto carve = [&](size_t bytes) {
        char* p = w;
        w += (bytes + 255) & ~(size_t)255;
        return p;
    };
    unsigned long long* packed = (unsigned long long*)carve((size_t)N * 8);
    float*          dis    = (float*)carve((size_t)N * 4);
    int*            rowptr = (int*)  carve((size_t)(N + 1) * 4);
    int*            part   = (int*)  carve(256 * 4);
    int2*           edges  = (int2*) carve((size_t)E * 8);
    unsigned short* W1T    = (unsigned short*)carve((size_t)DIN * DH * 2);
    unsigned short* W2T    = (unsigned short*)carve((size_t)DH * DOUT * 2);
    unsigned short* h1     = (unsigned short*)carve((size_t)N * DH * 2);
    unsigned short* h1ln   = (unsigned short*)carve((size_t)N * DH * 2);
    unsigned short* h2     = (unsigned short*)carve((size_t)N * DOUT * 2);
    // ord aliases h1 (dead before GEMM1 writes h1; stream-ordered => no race)
    int*            ord    = (int*)h1;

    const int gE = (E + 255) / 256;
    const int gN = (N + 255) / 256;     // nparts for scan (N<=65536)
    const int gW = (N + 3) / 4;         // one wave per node, 4 waves/block
    const int gG = (N + 63) / 64;       // GEMM blocks (BM=64)

    // ---- graph preprocessing: packed hist (1 atomic/edge), scan, CSR ----
    hipMemsetAsync(packed, 0, (size_t)N * 8, stream);
    k_hist    <<<gE, 256, 0, stream>>>(row, ew, packed, ord, E);
    k_dis_part<<<gN, 256, 0, stream>>>(packed, dis, part, N);
    k_scanpart<<<1, 256, 0, stream>>>(part, gN);
    k_rowptr  <<<gN, 256, 0, stream>>>(packed, part, rowptr, N);
    k_scatter <<<gE, 256, 0, stream>>>(row, col, ew, dis, rowptr, ord, edges, E);

    // ---- weights -> bf16 transposed (one launch) ----
    k_wt<<<(DIN * DH + DH * DOUT + 255) / 256, 256, 0, stream>>>(W1, W2, W1T, W2T);

    // ---- layer 1: h1 = bf16(x) @ W1 + b1 ----
    k_gemm_mfma<true, DH><<<gG, 256, 0, stream>>>(x, W1T, b1, h1, N, DIN);
    k_agg_ln<DH, true, true><<<gW, 256, 0, stream>>>(h1, rowptr, edges,
                                                     g1, be1, h1ln, N);

    // ---- layer 2: h2 = h1ln @ W2 + b2 ----
    k_gemm_mfma<false, DOUT><<<gG, 256, 0, stream>>>(h1ln, W2T, b2, h2, N, DH);
    k_agg_ln<DOUT, false, false><<<gW, 256, 0, stream>>>(h2, rowptr, edges,
                                                         g2, be2, out, N);
}